// Round 3
// baseline (844.691 us; speedup 1.0000x reference)
//
#include <hip/hip_runtime.h>
#include <hip/hip_cooperative_groups.h>

namespace cg = cooperative_groups;

#define BATCH   2048
#define IN_SZ   40960
#define IN4     (IN_SZ / 4)
#define HID     256
#define LCAP    64      // per-row per-perspective capacity (ACTIVE=30 max)
#define NB      1024    // cooperative grid: 4 blocks/CU x 256 CUs
#define ROWS_PB (BATCH / NB)   // = 2
#define NTILES  ((IN_SZ / 32) * (HID / 32))   // 10240 transpose tiles

// ---------------------------------------------------------------------------
// Single cooperative kernel.
//  Phase A1: grid-stride 32x32 LDS-tile transpose ft_w[HID][IN_SZ] -> ftT[IN_SZ][HID]
//  Phase A2: scan this block's 2 batch rows (both perspectives), LDS-compact
//            the nonzero feature indices (values are exactly 0.0/1.0).
//  grid.sync()
//  Phase B : per row: gather ftT rows + bias, clip, stm-concat, 512->32->32->1 MLP.
// ---------------------------------------------------------------------------
__global__ __launch_bounds__(256, 4) void nnue_one(
    const float* __restrict__ wo, const float* __restrict__ bo,
    const float* __restrict__ stm,
    const float* __restrict__ ftw, const float* __restrict__ ftb,
    const float* __restrict__ l1w, const float* __restrict__ l1b,
    const float* __restrict__ l2w, const float* __restrict__ l2b,
    const float* __restrict__ l3w, const float* __restrict__ l3b,
    float* __restrict__ ftT, float* __restrict__ out)
{
    __shared__ float tile[32][33];
    __shared__ int   idx[ROWS_PB][2][LCAP];
    __shared__ int   cnt[ROWS_PB][2];
    __shared__ float hidden[2 * HID];
    __shared__ float x1[32], x2[32];

    const int t   = threadIdx.x;
    const int blk = blockIdx.x;

    // ---- init LDS counters ----
    if (t < ROWS_PB * 2) ((int*)cnt)[t] = 0;

    // ---- Phase A1: transpose slice ----
    {
        const int tx = t & 31;        // 0..31
        const int ty = t >> 5;        // 0..7
        for (int tid = blk; tid < NTILES; tid += NB) {
            const int bx = tid >> 3;  // 0..1279 (IN tile)
            const int by = tid & 7;   // 0..7    (HID tile)
            __syncthreads();          // protect tile from previous iter
#pragma unroll
            for (int j = 0; j < 32; j += 8)
                tile[ty + j][tx] = ftw[(size_t)(by * 32 + ty + j) * IN_SZ + bx * 32 + tx];
            __syncthreads();
#pragma unroll
            for (int j = 0; j < 32; j += 8)
                ftT[(size_t)(bx * 32 + ty + j) * HID + by * 32 + tx] = tile[tx][ty + j];
        }
    }
    __syncthreads();   // cnt init + tile done before scan atomics

    // ---- Phase A2: scan this block's rows (the HBM-bound bulk) ----
    {
        const int row0 = blk * ROWS_PB;
        const float4* __restrict__ w0 = (const float4*)(wo + (size_t)row0 * IN_SZ);
        const float4* __restrict__ b0 = (const float4*)(bo + (size_t)row0 * IN_SZ);
        const float4* __restrict__ w1 = (const float4*)(wo + (size_t)(row0 + 1) * IN_SZ);
        const float4* __restrict__ b1 = (const float4*)(bo + (size_t)(row0 + 1) * IN_SZ);

        for (int i = t; i < IN4; i += 256) {
            const float4 a0 = w0[i];
            const float4 a1 = b0[i];
            const float4 a2 = w1[i];
            const float4 a3 = b1[i];
            const int f0 = 4 * i;
            // component values are exactly 0.0/1.0 -> sum test is exact
            if (((a0.x + a0.y) + (a0.z + a0.w)) != 0.f) {
                if (a0.x != 0.f) idx[0][0][atomicAdd(&cnt[0][0], 1)] = f0;
                if (a0.y != 0.f) idx[0][0][atomicAdd(&cnt[0][0], 1)] = f0 + 1;
                if (a0.z != 0.f) idx[0][0][atomicAdd(&cnt[0][0], 1)] = f0 + 2;
                if (a0.w != 0.f) idx[0][0][atomicAdd(&cnt[0][0], 1)] = f0 + 3;
            }
            if (((a1.x + a1.y) + (a1.z + a1.w)) != 0.f) {
                if (a1.x != 0.f) idx[0][1][atomicAdd(&cnt[0][1], 1)] = f0;
                if (a1.y != 0.f) idx[0][1][atomicAdd(&cnt[0][1], 1)] = f0 + 1;
                if (a1.z != 0.f) idx[0][1][atomicAdd(&cnt[0][1], 1)] = f0 + 2;
                if (a1.w != 0.f) idx[0][1][atomicAdd(&cnt[0][1], 1)] = f0 + 3;
            }
            if (((a2.x + a2.y) + (a2.z + a2.w)) != 0.f) {
                if (a2.x != 0.f) idx[1][0][atomicAdd(&cnt[1][0], 1)] = f0;
                if (a2.y != 0.f) idx[1][0][atomicAdd(&cnt[1][0], 1)] = f0 + 1;
                if (a2.z != 0.f) idx[1][0][atomicAdd(&cnt[1][0], 1)] = f0 + 2;
                if (a2.w != 0.f) idx[1][0][atomicAdd(&cnt[1][0], 1)] = f0 + 3;
            }
            if (((a3.x + a3.y) + (a3.z + a3.w)) != 0.f) {
                if (a3.x != 0.f) idx[1][1][atomicAdd(&cnt[1][1], 1)] = f0;
                if (a3.y != 0.f) idx[1][1][atomicAdd(&cnt[1][1], 1)] = f0 + 1;
                if (a3.z != 0.f) idx[1][1][atomicAdd(&cnt[1][1], 1)] = f0 + 2;
                if (a3.w != 0.f) idx[1][1][atomicAdd(&cnt[1][1], 1)] = f0 + 3;
            }
        }
    }

    // ---- grid-wide sync: ftT complete everywhere, lists complete locally ----
    cg::this_grid().sync();

    // ---- Phase B: per-row FT gather + MLP ----
    for (int r = 0; r < ROWS_PB; ++r) {
        const int row = blk * ROWS_PB + r;
        const int cw = cnt[r][0];
        const int cb = cnt[r][1];

        float accw = ftb[t];
        float accb = accw;
        for (int j = 0; j < cw; ++j) accw += ftT[(size_t)idx[r][0][j] * HID + t];
        for (int j = 0; j < cb; ++j) accb += ftT[(size_t)idx[r][1][j] * HID + t];
        accw = fminf(fmaxf(accw, 0.f), 1.f);
        accb = fminf(fmaxf(accb, 0.f), 1.f);

        const bool s = (stm[row] != 0.f);
        hidden[t]       = s ? accw : accb;
        hidden[HID + t] = s ? accb : accw;
        __syncthreads();

        // l1 (512 -> 32): 8 lanes per output, shuffle reduce
        {
            const int o = t >> 3;
            const int part = t & 7;
            const float* w1p = l1w + o * (2 * HID);
            float sum = 0.f;
#pragma unroll 8
            for (int i = part; i < 2 * HID; i += 8)
                sum += hidden[i] * w1p[i];
            sum += __shfl_xor(sum, 1);
            sum += __shfl_xor(sum, 2);
            sum += __shfl_xor(sum, 4);
            if (part == 0) x1[o] = fminf(fmaxf(sum + l1b[o], 0.f), 1.f);
        }
        __syncthreads();

        // l2 (32 -> 32)
        if (t < 32) {
            const float* w2 = l2w + t * 32;
            float sum = l2b[t];
#pragma unroll
            for (int i = 0; i < 32; ++i) sum += x1[i] * w2[i];
            x2[t] = fminf(fmaxf(sum, 0.f), 1.f);
        }
        __syncthreads();

        // l3 (32 -> 1)
        if (t == 0) {
            float sum = l3b[0];
#pragma unroll
            for (int i = 0; i < 32; ++i) sum += x2[i] * l3w[i];
            out[row] = sum;
        }
        __syncthreads();   // hidden/x1/x2 reuse next r
    }
}

// ---------------------------------------------------------------------------
// Fallback (ws too small or cooperative launch unavailable): fully fused,
// untransposed gather. Correct, ~R1 performance.
// ---------------------------------------------------------------------------
__global__ __launch_bounds__(256) void nnue_fused_fallback(
    const float* __restrict__ wo, const float* __restrict__ bo,
    const float* __restrict__ stm,
    const float* __restrict__ ftw, const float* __restrict__ ftb,
    const float* __restrict__ l1w, const float* __restrict__ l1b,
    const float* __restrict__ l2w, const float* __restrict__ l2b,
    const float* __restrict__ l3w, const float* __restrict__ l3b,
    float* __restrict__ out) {
    __shared__ int   idxw[LCAP], idxb[LCAP];
    __shared__ int   cntw, cntb;
    __shared__ float hidden[2 * HID];
    __shared__ float x1[32], x2[32];

    const int b = blockIdx.x;
    const int t = threadIdx.x;
    if (t == 0) { cntw = 0; cntb = 0; }
    __syncthreads();

    const float4* wrow = (const float4*)(wo + (size_t)b * IN_SZ);
    const float4* brow = (const float4*)(bo + (size_t)b * IN_SZ);
    for (int i = t; i < IN4; i += 256) {
        float4 v = wrow[i];
        float4 u = brow[i];
        if (((v.x + v.y) + (v.z + v.w)) != 0.f) {
            if (v.x != 0.f) idxw[atomicAdd(&cntw, 1)] = 4 * i;
            if (v.y != 0.f) idxw[atomicAdd(&cntw, 1)] = 4 * i + 1;
            if (v.z != 0.f) idxw[atomicAdd(&cntw, 1)] = 4 * i + 2;
            if (v.w != 0.f) idxw[atomicAdd(&cntw, 1)] = 4 * i + 3;
        }
        if (((u.x + u.y) + (u.z + u.w)) != 0.f) {
            if (u.x != 0.f) idxb[atomicAdd(&cntb, 1)] = 4 * i;
            if (u.y != 0.f) idxb[atomicAdd(&cntb, 1)] = 4 * i + 1;
            if (u.z != 0.f) idxb[atomicAdd(&cntb, 1)] = 4 * i + 2;
            if (u.w != 0.f) idxb[atomicAdd(&cntb, 1)] = 4 * i + 3;
        }
    }
    __syncthreads();

    float accw = ftb[t], accb = accw;
    for (int j = 0; j < cntw; ++j) accw += ftw[(size_t)t * IN_SZ + idxw[j]];
    for (int j = 0; j < cntb; ++j) accb += ftw[(size_t)t * IN_SZ + idxb[j]];
    accw = fminf(fmaxf(accw, 0.f), 1.f);
    accb = fminf(fmaxf(accb, 0.f), 1.f);

    const bool s = (stm[b] != 0.f);
    hidden[t]       = s ? accw : accb;
    hidden[HID + t] = s ? accb : accw;
    __syncthreads();

    {
        const int o = t >> 3, part = t & 7;
        const float* w1p = l1w + o * (2 * HID);
        float sum = 0.f;
        for (int i = part; i < 2 * HID; i += 8) sum += hidden[i] * w1p[i];
        sum += __shfl_xor(sum, 1);
        sum += __shfl_xor(sum, 2);
        sum += __shfl_xor(sum, 4);
        if (part == 0) x1[o] = fminf(fmaxf(sum + l1b[o], 0.f), 1.f);
    }
    __syncthreads();
    if (t < 32) {
        float sum = l2b[t];
        for (int i = 0; i < 32; ++i) sum += x1[i] * l2w[t * 32 + i];
        x2[t] = fminf(fmaxf(sum, 0.f), 1.f);
    }
    __syncthreads();
    if (t == 0) {
        float sum = l3b[0];
        for (int i = 0; i < 32; ++i) sum += x2[i] * l3w[i];
        out[b] = sum;
    }
}

extern "C" void kernel_launch(void* const* d_in, const int* in_sizes, int n_in,
                              void* d_out, int out_size, void* d_ws, size_t ws_size,
                              hipStream_t stream) {
    const float* wo  = (const float*)d_in[0];
    const float* bo  = (const float*)d_in[1];
    const float* stm = (const float*)d_in[2];
    const float* ftw = (const float*)d_in[3];
    const float* ftb = (const float*)d_in[4];
    const float* l1w = (const float*)d_in[5];
    const float* l1b = (const float*)d_in[6];
    const float* l2w = (const float*)d_in[7];
    const float* l2b = (const float*)d_in[8];
    const float* l3w = (const float*)d_in[9];
    const float* l3b = (const float*)d_in[10];
    float* out = (float*)d_out;

    const size_t ftT_bytes = (size_t)IN_SZ * HID * sizeof(float);   // 41.9 MB
    bool ok = false;
    if (ws_size >= ftT_bytes) {
        float* ftT = (float*)d_ws;
        void* args[] = { (void*)&wo, (void*)&bo, (void*)&stm, (void*)&ftw, (void*)&ftb,
                         (void*)&l1w, (void*)&l1b, (void*)&l2w, (void*)&l2b,
                         (void*)&l3w, (void*)&l3b, (void*)&ftT, (void*)&out };
        hipError_t rc = hipLaunchCooperativeKernel((const void*)nnue_one,
                                                   dim3(NB), dim3(256), args, 0, stream);
        ok = (rc == hipSuccess);
    }
    if (!ok) {
        nnue_fused_fallback<<<BATCH, 256, 0, stream>>>(wo, bo, stm, ftw, ftb,
                                                       l1w, l1b, l2w, l2b, l3w, l3b, out);
    }
}

// Round 4
// 691.783 us; speedup vs baseline: 1.2210x; 1.2210x over previous
//
#include <hip/hip_runtime.h>

#define BATCH 2048
#define IN_SZ 40960
#define IN4   (IN_SZ / 4)
#define HID   256
#define LCAP  64   // per-row per-perspective capacity (ACTIVE=30 max)

// ---------------------------------------------------------------------------
// Transpose ft_w [HID][IN_SZ] -> ftT [IN_SZ][HID] so per-feature gathers are
// contiguous 1KB rows. 32x32 LDS tile, padded to kill bank conflicts.
// ---------------------------------------------------------------------------
__global__ __launch_bounds__(256) void ft_transpose(const float* __restrict__ ftw,
                                                    float* __restrict__ ftT) {
    __shared__ float tile[32][33];
    const int tx = threadIdx.x;   // 0..31
    const int ty = threadIdx.y;   // 0..7
    const int bx = blockIdx.x;    // IN_SZ/32 = 1280
    const int by = blockIdx.y;    // HID/32  = 8

    const int col = bx * 32 + tx;               // IN index (coalesced read)
#pragma unroll
    for (int j = 0; j < 32; j += 8) {
        const int row = by * 32 + ty + j;       // HID index
        tile[ty + j][tx] = ftw[(size_t)row * IN_SZ + col];
    }
    __syncthreads();

    const int ocol = by * 32 + tx;              // HID index (coalesced write)
#pragma unroll
    for (int j = 0; j < 32; j += 8) {
        const int orow = bx * 32 + ty + j;      // IN index
        ftT[(size_t)orow * HID + ocol] = tile[tx][ty + j];
    }
}

// ---------------------------------------------------------------------------
// One block per batch row (2048 blocks, 8/CU, 32 waves/CU).
//  Phase 1: uint4 scan of white/black rows, 2x unrolled (4 loads in flight),
//           integer nonzero test (exact: values are 0.0f/1.0f bit patterns),
//           wave-level __any fast path skips per-component branches.
//  Phase 2: per-thread-h gather of ftT rows + bias, clip.
//  Phase 3: stm-ordered concat; l1 (512->32) 8-lane shuffle reduce;
//           l2 (32->32); l3 (32->1).
// ---------------------------------------------------------------------------
__global__ __launch_bounds__(256) void nnue_fused(
    const float* __restrict__ wo, const float* __restrict__ bo,
    const float* __restrict__ stm,
    const float* __restrict__ ftT,   // [IN_SZ][HID]
    const float* __restrict__ ftb,
    const float* __restrict__ l1w, const float* __restrict__ l1b,
    const float* __restrict__ l2w, const float* __restrict__ l2b,
    const float* __restrict__ l3w, const float* __restrict__ l3b,
    float* __restrict__ out) {
    __shared__ int   idxw[LCAP], idxb[LCAP];
    __shared__ int   cntw, cntb;
    __shared__ float hidden[2 * HID];
    __shared__ float x1[32], x2[32];

    const int b = blockIdx.x;
    const int t = threadIdx.x;

    if (t == 0) { cntw = 0; cntb = 0; }
    __syncthreads();

    // ---- phase 1: streaming scan (the HBM-bound bulk: 320KB per block) ----
    {
        const uint4* __restrict__ wrow = (const uint4*)(wo + (size_t)b * IN_SZ);
        const uint4* __restrict__ brow = (const uint4*)(bo + (size_t)b * IN_SZ);
#pragma unroll 1
        for (int i0 = t; i0 < IN4; i0 += 512) {       // 20 iterations
            const int i1 = i0 + 256;
            const uint4 w0 = wrow[i0];
            const uint4 w1 = wrow[i1];
            const uint4 b0 = brow[i0];
            const uint4 b1 = brow[i1];
            const unsigned mw0 = w0.x | w0.y | w0.z | w0.w;
            const unsigned mw1 = w1.x | w1.y | w1.z | w1.w;
            const unsigned mb0 = b0.x | b0.y | b0.z | b0.w;
            const unsigned mb1 = b1.x | b1.y | b1.z | b1.w;
            if (__any(mw0 | mw1)) {                    // rare (~25%/wave-iter)
                if (w0.x) idxw[atomicAdd(&cntw, 1)] = 4 * i0;
                if (w0.y) idxw[atomicAdd(&cntw, 1)] = 4 * i0 + 1;
                if (w0.z) idxw[atomicAdd(&cntw, 1)] = 4 * i0 + 2;
                if (w0.w) idxw[atomicAdd(&cntw, 1)] = 4 * i0 + 3;
                if (w1.x) idxw[atomicAdd(&cntw, 1)] = 4 * i1;
                if (w1.y) idxw[atomicAdd(&cntw, 1)] = 4 * i1 + 1;
                if (w1.z) idxw[atomicAdd(&cntw, 1)] = 4 * i1 + 2;
                if (w1.w) idxw[atomicAdd(&cntw, 1)] = 4 * i1 + 3;
            }
            if (__any(mb0 | mb1)) {
                if (b0.x) idxb[atomicAdd(&cntb, 1)] = 4 * i0;
                if (b0.y) idxb[atomicAdd(&cntb, 1)] = 4 * i0 + 1;
                if (b0.z) idxb[atomicAdd(&cntb, 1)] = 4 * i0 + 2;
                if (b0.w) idxb[atomicAdd(&cntb, 1)] = 4 * i0 + 3;
                if (b1.x) idxb[atomicAdd(&cntb, 1)] = 4 * i1;
                if (b1.y) idxb[atomicAdd(&cntb, 1)] = 4 * i1 + 1;
                if (b1.z) idxb[atomicAdd(&cntb, 1)] = 4 * i1 + 2;
                if (b1.w) idxb[atomicAdd(&cntb, 1)] = 4 * i1 + 3;
            }
        }
    }
    __syncthreads();

    // ---- phase 2: feature-transformer gather (h = t) ----
    const int cw = cntw, cb = cntb;
    float accw = ftb[t];
    float accb = accw;
    for (int j = 0; j < cw; ++j) accw += ftT[(size_t)idxw[j] * HID + t];
    for (int j = 0; j < cb; ++j) accb += ftT[(size_t)idxb[j] * HID + t];
    accw = fminf(fmaxf(accw, 0.f), 1.f);
    accb = fminf(fmaxf(accb, 0.f), 1.f);

    // ---- phase 3: stm-ordered concat ----
    const bool s = (stm[b] != 0.f);
    hidden[t]       = s ? accw : accb;
    hidden[HID + t] = s ? accb : accw;
    __syncthreads();

    // l1 (512 -> 32): 8 lanes per output, shuffle reduce
    {
        const int o = t >> 3;              // 0..31
        const int part = t & 7;            // 0..7
        const float* w1p = l1w + o * (2 * HID);
        float sum = 0.f;
#pragma unroll 8
        for (int i = part; i < 2 * HID; i += 8)
            sum += hidden[i] * w1p[i];
        sum += __shfl_xor(sum, 1);
        sum += __shfl_xor(sum, 2);
        sum += __shfl_xor(sum, 4);
        if (part == 0) x1[o] = fminf(fmaxf(sum + l1b[o], 0.f), 1.f);
    }
    __syncthreads();

    // l2 (32 -> 32)
    if (t < 32) {
        const float* w2 = l2w + t * 32;
        float sum = l2b[t];
#pragma unroll
        for (int i = 0; i < 32; ++i) sum += x1[i] * w2[i];
        x2[t] = fminf(fmaxf(sum, 0.f), 1.f);
    }
    __syncthreads();

    // l3 (32 -> 1)
    if (t == 0) {
        float sum = l3b[0];
#pragma unroll
        for (int i = 0; i < 32; ++i) sum += x2[i] * l3w[i];
        out[b] = sum;
    }
}

// ---------------------------------------------------------------------------
// Fallback (ws too small): untransposed strided gather. Correct, slower.
// ---------------------------------------------------------------------------
__global__ __launch_bounds__(256) void nnue_fused_fallback(
    const float* __restrict__ wo, const float* __restrict__ bo,
    const float* __restrict__ stm,
    const float* __restrict__ ftw, const float* __restrict__ ftb,
    const float* __restrict__ l1w, const float* __restrict__ l1b,
    const float* __restrict__ l2w, const float* __restrict__ l2b,
    const float* __restrict__ l3w, const float* __restrict__ l3b,
    float* __restrict__ out) {
    __shared__ int   idxw[LCAP], idxb[LCAP];
    __shared__ int   cntw, cntb;
    __shared__ float hidden[2 * HID];
    __shared__ float x1[32], x2[32];

    const int b = blockIdx.x;
    const int t = threadIdx.x;
    if (t == 0) { cntw = 0; cntb = 0; }
    __syncthreads();

    const uint4* wrow = (const uint4*)(wo + (size_t)b * IN_SZ);
    const uint4* brow = (const uint4*)(bo + (size_t)b * IN_SZ);
    for (int i = t; i < IN4; i += 256) {
        uint4 v = wrow[i];
        uint4 u = brow[i];
        if (v.x | v.y | v.z | v.w) {
            if (v.x) idxw[atomicAdd(&cntw, 1)] = 4 * i;
            if (v.y) idxw[atomicAdd(&cntw, 1)] = 4 * i + 1;
            if (v.z) idxw[atomicAdd(&cntw, 1)] = 4 * i + 2;
            if (v.w) idxw[atomicAdd(&cntw, 1)] = 4 * i + 3;
        }
        if (u.x | u.y | u.z | u.w) {
            if (u.x) idxb[atomicAdd(&cntb, 1)] = 4 * i;
            if (u.y) idxb[atomicAdd(&cntb, 1)] = 4 * i + 1;
            if (u.z) idxb[atomicAdd(&cntb, 1)] = 4 * i + 2;
            if (u.w) idxb[atomicAdd(&cntb, 1)] = 4 * i + 3;
        }
    }
    __syncthreads();

    float accw = ftb[t], accb = accw;
    for (int j = 0; j < cntw; ++j) accw += ftw[(size_t)t * IN_SZ + idxw[j]];
    for (int j = 0; j < cntb; ++j) accb += ftw[(size_t)t * IN_SZ + idxb[j]];
    accw = fminf(fmaxf(accw, 0.f), 1.f);
    accb = fminf(fmaxf(accb, 0.f), 1.f);

    const bool s = (stm[b] != 0.f);
    hidden[t]       = s ? accw : accb;
    hidden[HID + t] = s ? accb : accw;
    __syncthreads();

    {
        const int o = t >> 3, part = t & 7;
        const float* w1p = l1w + o * (2 * HID);
        float sum = 0.f;
        for (int i = part; i < 2 * HID; i += 8) sum += hidden[i] * w1p[i];
        sum += __shfl_xor(sum, 1);
        sum += __shfl_xor(sum, 2);
        sum += __shfl_xor(sum, 4);
        if (part == 0) x1[o] = fminf(fmaxf(sum + l1b[o], 0.f), 1.f);
    }
    __syncthreads();
    if (t < 32) {
        float sum = l2b[t];
        for (int i = 0; i < 32; ++i) sum += x1[i] * l2w[t * 32 + i];
        x2[t] = fminf(fmaxf(sum, 0.f), 1.f);
    }
    __syncthreads();
    if (t == 0) {
        float sum = l3b[0];
        for (int i = 0; i < 32; ++i) sum += x2[i] * l3w[i];
        out[b] = sum;
    }
}

extern "C" void kernel_launch(void* const* d_in, const int* in_sizes, int n_in,
                              void* d_out, int out_size, void* d_ws, size_t ws_size,
                              hipStream_t stream) {
    const float* wo  = (const float*)d_in[0];
    const float* bo  = (const float*)d_in[1];
    const float* stm = (const float*)d_in[2];
    const float* ftw = (const float*)d_in[3];
    const float* ftb = (const float*)d_in[4];
    const float* l1w = (const float*)d_in[5];
    const float* l1b = (const float*)d_in[6];
    const float* l2w = (const float*)d_in[7];
    const float* l2b = (const float*)d_in[8];
    const float* l3w = (const float*)d_in[9];
    const float* l3b = (const float*)d_in[10];
    float* out = (float*)d_out;

    const size_t ftT_bytes = (size_t)IN_SZ * HID * sizeof(float);   // 41.9 MB
    if (ws_size >= ftT_bytes) {
        float* ftT = (float*)d_ws;
        ft_transpose<<<dim3(IN_SZ / 32, HID / 32), dim3(32, 8), 0, stream>>>(ftw, ftT);
        nnue_fused<<<BATCH, 256, 0, stream>>>(wo, bo, stm, ftT, ftb,
                                              l1w, l1b, l2w, l2b, l3w, l3b, out);
    } else {
        nnue_fused_fallback<<<BATCH, 256, 0, stream>>>(wo, bo, stm, ftw, ftb,
                                                       l1w, l1b, l2w, l2b, l3w, l3b, out);
    }
}